// Round 9
// baseline (224.245 us; speedup 1.0000x reference)
//
#include <hip/hip_runtime.h>

typedef unsigned short u16;
typedef unsigned int u32;
typedef __attribute__((ext_vector_type(8))) __bf16 bf16x8;
typedef __attribute__((ext_vector_type(4))) float f32x4;
typedef __attribute__((ext_vector_type(16))) float f32x16;

#define EMBED 1024
#define NB 2
#define LQ 2048
#define HEADS 16
#define DH 64
// log2(e) / sqrt(64) -- folded into Q at projection time
#define QSCALE 0.18033688011112042f

__device__ __forceinline__ u16 f2bf(float f) {
  u32 u = __float_as_uint(f);
  u32 r = (u + 0x7FFFu + ((u >> 16) & 1u)) >> 16;  // RNE
  return (u16)r;
}

__device__ __forceinline__ void glds16(const void* g, void* l) {
  __builtin_amdgcn_global_load_lds((const __attribute__((address_space(1))) void*)g,
                                   (__attribute__((address_space(3))) void*)l, 16, 0, 0);
}

__device__ __forceinline__ f32x4 mfma16(bf16x8 a, bf16x8 b, f32x4 c) {
  return __builtin_amdgcn_mfma_f32_16x16x32_bf16(a, b, c, 0, 0, 0);
}
__device__ __forceinline__ f32x16 mfma32(bf16x8 a, bf16x8 b, f32x16 c) {
  return __builtin_amdgcn_mfma_f32_32x32x16_bf16(a, b, c, 0, 0, 0);
}

// v_permlane32_swap_b32: a[l>=32] <-> b[l-32]. Register-only exchange.
__device__ __forceinline__ void pl32(u32& a, u32& b) {
  asm("v_permlane32_swap_b32 %0, %1" : "+v"(a), "+v"(b));
}

// pack two floats to bf16 pair (truncating): low = a, high = b
__device__ __forceinline__ u32 packbf(float a, float b) {
  return __builtin_amdgcn_perm(__float_as_uint(b), __float_as_uint(a), 0x07060302u);
}

// ---------------- cast fp32 -> bf16 for activations + weights ----------------
__global__ __launch_bounds__(256) void cast_kernel(
    const float* __restrict__ q, const float* __restrict__ kv,
    const float* __restrict__ wq, const float* __restrict__ wk,
    const float* __restrict__ wv, const float* __restrict__ wo,
    u16* __restrict__ qb, u16* __restrict__ kvb, u16* __restrict__ wqb,
    u16* __restrict__ wkb, u16* __restrict__ wvb, u16* __restrict__ wob) {
  int bid = blockIdx.x;
  const float* src;
  u16* dst;
  long base;
  if (bid < 2048) {
    src = q; dst = qb; base = (long)bid * 2048;
  } else if (bid < 4096) {
    src = kv; dst = kvb; base = (long)(bid - 2048) * 2048;
  } else {
    int wsel = (bid - 4096) >> 9;
    int wb = (bid - 4096) & 511;
    if (wsel == 0) { src = wq; dst = wqb; }
    else if (wsel == 1) { src = wk; dst = wkb; }
    else if (wsel == 2) { src = wv; dst = wvb; }
    else { src = wo; dst = wob; }
    base = (long)wb * 2048;
  }
  long e = base + (long)threadIdx.x * 8;
  float4 f0 = *(const float4*)(src + e);
  float4 f1 = *(const float4*)(src + e + 4);
  uint4 o;
  o.x = (u32)f2bf(f0.x) | ((u32)f2bf(f0.y) << 16);
  o.y = (u32)f2bf(f0.z) | ((u32)f2bf(f0.w) << 16);
  o.z = (u32)f2bf(f1.x) | ((u32)f2bf(f1.y) << 16);
  o.w = (u32)f2bf(f1.z) | ((u32)f2bf(f1.w) << 16);
  *(uint4*)(dst + e) = o;
}

// ------------- GEMM: C = A @ W^T, ring-3 BK=32, 1 counted barrier/step ------
// R8 post-mortem: the old 2-full-drain-barriers-per-K-step exposed the
// just-issued stage's L2 latency 32x per block (MfmaUtil 19%). T3/T4 fix,
// same schedule proven in attn's ring: stage tile t+2 into slot (t+2)%3
// (3 vm ops/thread), compute tile t, then s_waitcnt vmcnt(3)+s_barrier --
// tile t+1 (issued last step) is older than the newest 3 ops, so it is
// guaranteed landed; this step's stage stays in flight across the barrier.
// LDS 3 x (A 4KB + B 8KB) = 36KB -> 4 blocks/CU kept. Swizzle for 32-col
// rows: chunk ^ ((row>>1)&3) (2-way max on both ds path sides -> free).
// K-chunk accumulation order unchanged vs BK=64/ki -> bitwise-identical
// results (absmax tripwire). Epilogues: R7's coalesced scalar forms
// (R8's lane-vectorized forms were 128B/4KB-strided -> reverted).
// mode 0: Q -> [bh][L][64] scaled; 1: K same; 2: V^T b64 stores; 3: fp32+resid.
template <int IT>
__device__ __forceinline__ void gemm_core(
    u16* AsB, u16* BsB, const u16* __restrict__ A, const u16* __restrict__ W,
    const float* __restrict__ bias, const float* __restrict__ resid,
    void* __restrict__ outp, int mode, int bx, int by) {
  const int K = EMBED;
  const int TM = IT * 32;
  const int tid = threadIdx.x;
  const int lane = tid & 63;
  const int wv = tid >> 6;
  const int wm = wv >> 1, wn = wv & 1;
  const int l16 = lane & 15, quad = lane >> 4;
  const long tile_m = (long)bx * TM;
  const long tile_n = (long)by * 128;

  f32x4 z4 = {0.f, 0.f, 0.f, 0.f};
  f32x4 acc[IT][4];
#pragma unroll
  for (int i = 0; i < IT; i++)
#pragma unroll
    for (int j = 0; j < 4; j++) acc[i][j] = z4;

// stage K-tile t (cols t*32..t*32+31) into ring slot S (literal).
// A: TM rows x 4 chunks(16B) = 1 op/thread (IT=2); B: 128 x 4 = 2 ops.
#define GSTAGE(t, S)                                                            \
  do {                                                                          \
    _Pragma("unroll") for (int it2 = 0; it2 < (TM * 4) / 256; it2++) {          \
      int lin = it2 * 256 + tid;                                                \
      int row = lin >> 2, cc = lin & 3;                                         \
      glds16(A + (tile_m + row) * K + (t) * 32 +                                \
                 ((cc ^ ((row >> 1) & 3)) << 3),                                \
             AsB + (S) * (TM * 32) + lin * 8);                                  \
    }                                                                           \
    _Pragma("unroll") for (int it2 = 0; it2 < 2; it2++) {                       \
      int lin = it2 * 256 + tid;                                                \
      int row = lin >> 2, cc = lin & 3;                                         \
      glds16(W + (tile_n + row) * K + (t) * 32 +                                \
                 ((cc ^ ((row >> 1) & 3)) << 3),                                \
             BsB + (S) * (128 * 32) + lin * 8);                                 \
    }                                                                           \
  } while (0)

// compute K-tile from ring slot S: 6 ds_read_b128 + 8 mfma16 (IT=2)
#define GCOMP(S)                                                                \
  do {                                                                          \
    bf16x8 af[IT], bfr[4];                                                      \
    _Pragma("unroll") for (int i = 0; i < IT; i++) {                            \
      int row = wm * (IT * 16) + i * 16 + l16;                                  \
      af[i] = *(const bf16x8*)(AsB + (S) * (TM * 32) + row * 32 +               \
                               ((quad ^ ((row >> 1) & 3)) << 3));               \
    }                                                                           \
    _Pragma("unroll") for (int j = 0; j < 4; j++) {                             \
      int row = wn * 64 + j * 16 + l16;                                         \
      bfr[j] = *(const bf16x8*)(BsB + (S) * (128 * 32) + row * 32 +             \
                                ((quad ^ ((row >> 1) & 3)) << 3));              \
    }                                                                           \
    _Pragma("unroll") for (int i = 0; i < IT; i++)                              \
      _Pragma("unroll") for (int j = 0; j < 4; j++)                             \
          acc[i][j] = mfma16(af[i], bfr[j], acc[i][j]);                         \
  } while (0)

#define GSYNC(W_)                                                               \
  do {                                                                          \
    asm volatile("s_waitcnt vmcnt(" #W_ ")" ::: "memory");                      \
    __builtin_amdgcn_s_barrier();                                               \
    asm volatile("" ::: "memory");                                              \
  } while (0)

  GSTAGE(0, 0);
  GSTAGE(1, 1);
  GSYNC(3);  // tile 0 landed; tile 1's 3 ops may fly
  for (int t0 = 0; t0 < 30; t0 += 3) {  // steps t = 0..29, staging t+2
    GSTAGE(t0 + 2, 2);
    GCOMP(0);
    GSYNC(3);
    GSTAGE(t0 + 3, 0);
    GCOMP(1);
    GSYNC(3);
    GSTAGE(t0 + 4, 1);
    GCOMP(2);
    GSYNC(3);
  }
  GCOMP(0);   // t = 30 (slot 0); tile 31 may still fly
  GSYNC(0);   // full drain: tile 31 landed for all waves
  GCOMP(1);   // t = 31 (slot 1)

#undef GSTAGE
#undef GCOMP
#undef GSYNC

  // epilogue: C/D layout col=lane&15, row=quad*4+r
#pragma unroll
  for (int j = 0; j < 4; j++) {
    int gn = (int)tile_n + wn * 64 + j * 16 + l16;
    float bv = bias[gn];
#pragma unroll
    for (int i = 0; i < IT; i++) {
      long gm0 = tile_m + wm * (IT * 16) + i * 16 + quad * 4;
      if (mode == 3) {
#pragma unroll
        for (int r = 0; r < 4; r++) {
          long idx = (gm0 + r) * EMBED + gn;
          ((float*)outp)[idx] = acc[i][j][r] + bv + resid[idx];
        }
      } else if (mode == 2) {
        // V^T: lane's 4 values are consecutive l at fixed dh -> one b64 store
        int b = (int)(gm0 >> 11), l = (int)(gm0 & 2047);
        int hh = gn >> 6, dh = gn & 63;
        uint2 pk;
        pk.x = (u32)f2bf(acc[i][j][0] + bv) | ((u32)f2bf(acc[i][j][1] + bv) << 16);
        pk.y = (u32)f2bf(acc[i][j][2] + bv) | ((u32)f2bf(acc[i][j][3] + bv) << 16);
        *(uint2*)((u16*)outp + (long)((b * HEADS + hh) * DH + dh) * LQ + l) = pk;
      } else {
#pragma unroll
        for (int r = 0; r < 4; r++) {
          long gm = gm0 + r;
          float v = acc[i][j][r] + bv;
          if (mode == 0) v *= QSCALE;
          int b = (int)(gm >> 11), l = (int)(gm & 2047);
          int hh = gn >> 6, dh = gn & 63;
          ((u16*)outp)[(long)((b * HEADS + hh) * LQ + l) * DH + dh] = f2bf(v);
        }
      }
    }
  }
}

// IT=2 (64-row tiles): 1536 blocks, 4 blocks/CU (36KB LDS) for TLP.
__global__ __launch_bounds__(256, 4) void qkv_kernel(
    const u16* __restrict__ qb, const u16* __restrict__ kvb,
    const u16* __restrict__ wqb, const u16* __restrict__ wkb, const u16* __restrict__ wvb,
    const float* __restrict__ bq, const float* __restrict__ bk, const float* __restrict__ bv,
    u16* __restrict__ Qh, u16* __restrict__ Kh, u16* __restrict__ Vt) {
  __shared__ u16 As[3 * 64 * 32];    // 12 KB ring
  __shared__ u16 Bs[3 * 128 * 32];   // 24 KB ring
  if (blockIdx.z == 0)      gemm_core<2>(As, Bs, qb,  wqb, bq, nullptr, Qh, 0, blockIdx.x, blockIdx.y);
  else if (blockIdx.z == 1) gemm_core<2>(As, Bs, kvb, wkb, bk, nullptr, Kh, 1, blockIdx.x, blockIdx.y);
  else                      gemm_core<2>(As, Bs, kvb, wvb, bv, nullptr, Vt, 2, blockIdx.x, blockIdx.y);
}

__global__ __launch_bounds__(256, 4) void oproj_kernel(
    const u16* __restrict__ ctx, const u16* __restrict__ wob,
    const float* __restrict__ bo, const float* __restrict__ resid, float* __restrict__ out) {
  __shared__ u16 As[3 * 64 * 32];    // 12 KB ring
  __shared__ u16 Bs[3 * 128 * 32];   // 24 KB ring
  gemm_core<2>(As, Bs, ctx, wob, bo, resid, out, 3, blockIdx.x, blockIdx.y);
}

// ---- flash attention: 8-wave blocks (4 qsub x 2 key-halves), ring-4+vmcnt ---
// Verified at 44.3us (R8): 512 threads = 8 waves = 4 qsub x 2 key-halves;
// wave (qsub,kh) owns 32 qrows x keys [32kh,32kh+32) of each 64-key tile;
// 2 blocks/CU = 4 waves/SIMD. ring-4 (slot t&3), stage t+2, counted
// s_waitcnt vmcnt(2), XCD swizzle (FETCH 70->12 MB verified). K-half partials
// merge additively via one LDS exchange reusing the ring after the loop.
__global__ __launch_bounds__(512, 4) void attn_kernel(
    const u16* __restrict__ Qh, const u16* __restrict__ Kh,
    const u16* __restrict__ Vt, u16* __restrict__ ctx) {
  __shared__ u16 KVs[4][2][64 * 64];  // 64 KB: ring[4] x [K/V] x 64x64
  const int tid = threadIdx.x;
  const int lane = tid & 63;
  const int wv = tid >> 6;            // 8 waves
  const int qsub = wv >> 1;           // 4 q-subtiles of 32 rows
  const int kh = wv & 1;              // key half within each 64-key tile
  const int l32 = lane & 31, h = lane >> 5;
  // XCD swizzle (XCD = blockIdx%8): XCD x -> swz in [64x, 64x+64) -> bh chunk
  const int bid = (int)blockIdx.x;
  const int swz = (bid & 7) * 64 + (bid >> 3);
  const int bh = swz >> 4, qt = swz & 15;
  const long qoff = (long)bh * (LQ * DH) + (long)qt * (128 * DH);
  const long koff = (long)bh * (LQ * DH);
  const long voff = (long)bh * (DH * LQ);
  const int qbase = qsub * 32;
  const int krow = kh * 32 + l32;     // wave's K-row (key) in the 64-key tile

// stage K/V tile t into ring slot N; 512 threads cover 8KB each in ONE pass
// -> 2 vm ops per wave per stage
#define STAGE_KV(t, N)                                                          \
  do {                                                                          \
    int row = tid >> 3, cc = tid & 7;                                           \
    glds16(Kh + koff + (long)((t) * 64 + row) * 64 + ((cc ^ (row & 7)) << 3),   \
           &KVs[N][0][0] + tid * 8);                                            \
    glds16(Vt + voff + (long)row * LQ + (t) * 64 + ((cc ^ (row & 7)) << 3),     \
           &KVs[N][1][0] + tid * 8);                                            \
  } while (0)

// counted-drain barrier: allow the W newest vmem ops to stay in flight.
#define SYNC(W)                                                                 \
  do {                                                                          \
    asm volatile("s_waitcnt vmcnt(" #W ")" ::: "memory");                       \
    __builtin_amdgcn_s_barrier();                                               \
    asm volatile("" ::: "memory");                                              \
  } while (0)

  // Q B-frags direct from global: qrow = qbase+l32, d-chunk = ks*16+8h+(0..7)
  bf16x8 bq[4];
  {
    const u16* qp = Qh + qoff + (qbase + l32) * 64 + h * 8;
#pragma unroll
    for (int ks = 0; ks < 4; ks++) bq[ks] = *(const bf16x8*)(qp + ks * 16);
  }

  STAGE_KV(0, 0);
  STAGE_KV(1, 1);
  STAGE_KV(2, 2);
  SYNC(2);  // bq + tiles 0,1 landed; tile 2's 2 ops may fly

  f32x16 z16 = {0.f, 0.f, 0.f, 0.f, 0.f, 0.f, 0.f, 0.f,
                0.f, 0.f, 0.f, 0.f, 0.f, 0.f, 0.f, 0.f};
  f32x16 ot[2];
  ot[0] = z16;
  ot[1] = z16;
  f32x16 st;            // S^T scores for this wave's 32 keys x 32 qrows
  uint2 pk[4];          // packed exp'd scores (this wave's key half)
  float2 ls2 = {0.f, 0.f};

// S^T = K(half kh) . Q^T from ring slot C into st; inline ds_reads.
// ks==0 uses the hoisted zero vector as C -> no accumulator zero-init movs.
#define DO_S(C)                                                                  \
  do {                                                                           \
    __builtin_amdgcn_s_setprio(1);                                               \
    _Pragma("unroll") for (int ks = 0; ks < 4; ks++) {                           \
      bf16x8 ak = *(const bf16x8*)(&KVs[C][0][0] + krow * 64 +                   \
                                   (((ks * 2 + h) ^ (krow & 7)) << 3));          \
      st = mfma32(ak, bq[ks], (ks == 0) ? z16 : st);                             \
    }                                                                            \
    __builtin_amdgcn_s_setprio(0);                                               \
  } while (0)

// p = 2^st via raw v_exp_f32; lane's scores: qrow = qbase+l32,
// key = 32kh + 8g + 4h + r
#define DO_SM()                                                                  \
  do {                                                                           \
    _Pragma("unroll") for (int g = 0; g < 4; g++) {                              \
      float p0 = __builtin_amdgcn_exp2f(st[g * 4 + 0]);                          \
      float p1 = __builtin_amdgcn_exp2f(st[g * 4 + 1]);                          \
      float p2 = __builtin_amdgcn_exp2f(st[g * 4 + 2]);                          \
      float p3 = __builtin_amdgcn_exp2f(st[g * 4 + 3]);                          \
      ls2.x += p0 + p2;                                                          \
      ls2.y += p1 + p3;                                                          \
      pk[g].x = packbf(p0, p1);                                                  \
      pk[g].y = packbf(p2, p3);                                                  \
    }                                                                            \
  } while (0)

// O^T(partial over this wave's keys) += V^T . P from ring slot P.
// kstep s' in {0,1} covers keys 32kh+16s'..+15; B-frag words (keys
// 32kh+16s'+8h+{0..7}) from own pk + cross-half partner via permlane32_swap.
// V^T chunk c = (2*(2kh+s')+h) -> keys c*8..c*8+7.
#define DO_PV(P)                                                                 \
  do {                                                                           \
    _Pragma("unroll") for (int s = 0; s < 2; s++) {                              \
      uint2 wa = pk[s * 2];                                                      \
      uint2 wb = pk[s * 2 + 1];                                                  \
      u32 a0 = wa.x, b0 = wb.x, a1 = wa.y, b1 = wb.y;                            \
      pl32(a0, b0);                                                              \
      pl32(a1, b1);                                                              \
      union { u32 u[4]; bf16x8 v; } bp;                                          \
      bp.u[0] = a0;                                                              \
      bp.u[1] = a1;                                                              \
      bp.u[2] = b0;                                                              \
      bp.u[3] = b1;                                                              \
      __builtin_amdgcn_s_setprio(1);                                             \
      _Pragma("unroll") for (int mt2 = 0; mt2 < 2; mt2++) {                      \
        int row = mt2 * 32 + l32;                                                \
        int c = ((2 * kh + s) << 1) + h;                                         \
        bf16x8 av = *(const bf16x8*)(&KVs[P][1][0] + row * 64 +                  \
                                     ((c ^ (row & 7)) << 3));                    \
        ot[mt2] = mfma32(av, bp.v, ot[mt2]);                                     \
      }                                                                          \
      __builtin_amdgcn_s_setprio(0);                                             \
    }                                                                            \
  } while (0)

// iteration (tile kt): stage kt+2 -> N; softmax of kt-1 (st, WAR before S
// overwrites); S of kt from C; PV of kt-1 from P; counted barrier.
#define AITER(kt, P, C, N, W)                                                    \
  do {                                                                           \
    if ((kt) + 2 < 32) STAGE_KV((kt) + 2, N);                                    \
    DO_SM();                                                                     \
    DO_S(C);                                                                     \
    DO_PV(P);                                                                    \
    SYNC(W);                                                                     \
  } while (0)

  DO_S(0);  // prologue: scores of tile 0 (softmax'd in iter 1)

  AITER(1, 0, 1, 3, 2);
  for (int k0 = 2; k0 < 30; k0 += 4) {  // k0 = 2,6,...,26 -> kt = 2..29
    AITER(k0 + 0, 1, 2, 0, 2);
    AITER(k0 + 1, 2, 3, 1, 2);
    AITER(k0 + 2, 3, 0, 2, 2);
    AITER(k0 + 3, 0, 1, 3, 2);
  }
  AITER(30, 1, 2, 0, 0);  // no stage; full drain so tile 31 is landed
  AITER(31, 2, 3, 1, 0);  // no stage
  // tail: softmax + PV of tile 31 (slot 3)
  DO_SM();
  DO_PV(3);

#undef STAGE_KV
#undef SYNC
#undef DO_S
#undef DO_SM
#undef DO_PV
#undef AITER

  // partial lsum: fold float2 + combine the two lane-halves (same qrow)
  float lsum = ls2.x + ls2.y;
  lsum += __shfl_xor(lsum, 32);

  // ---- merge the two key-halves (additive; ring LDS reused) ----
  // mrg[qsub][lane][36pad]: 36 floats stride = 144B (16B-aligned, 4-way max)
  float* mrgf = (float*)(&KVs[0][0][0]);
  float* mlsf = mrgf + 4 * 64 * 36;  // 36864B + 1KB <= 64KB
  __syncthreads();  // all ring reads done before overwrite
  if (kh == 1) {
    int mbase = (qsub * 64 + lane) * 36;
#pragma unroll
    for (int mt2 = 0; mt2 < 2; mt2++)
#pragma unroll
      for (int e = 0; e < 16; e++) mrgf[mbase + mt2 * 16 + e] = ot[mt2][e];
    mlsf[qsub * 64 + lane] = lsum;
  }
  __syncthreads();
  if (kh == 0) {
    int mbase = (qsub * 64 + lane) * 36;
    lsum += mlsf[qsub * 64 + lane];
    float inv = 1.0f / lsum;
    // epilogue: lane holds qrow = qt*128 + qbase + l32, d = mt2*32 + g*8+4h+r
    const int b = bh >> 4, head = bh & 15;
    int qrow = qt * 128 + qbase + l32;
    long base = (long)(b * LQ + qrow) * EMBED + head * DH;
#pragma unroll
    for (int mt2 = 0; mt2 < 2; mt2++) {
#pragma unroll
      for (int g = 0; g < 4; g++) {
        float o0 = (ot[mt2][g * 4 + 0] + mrgf[mbase + mt2 * 16 + g * 4 + 0]) * inv;
        float o1 = (ot[mt2][g * 4 + 1] + mrgf[mbase + mt2 * 16 + g * 4 + 1]) * inv;
        float o2 = (ot[mt2][g * 4 + 2] + mrgf[mbase + mt2 * 16 + g * 4 + 2]) * inv;
        float o3 = (ot[mt2][g * 4 + 3] + mrgf[mbase + mt2 * 16 + g * 4 + 3]) * inv;
        uint2 pkk;
        pkk.x = (u32)f2bf(o0) | ((u32)f2bf(o1) << 16);
        pkk.y = (u32)f2bf(o2) | ((u32)f2bf(o3) << 16);
        *(uint2*)(ctx + base + mt2 * 32 + g * 8 + 4 * h) = pkk;
      }
    }
  }
}

// ---------------- LayerNorm in place on d_out ----------------
__global__ __launch_bounds__(256) void ln_kernel(
    float* __restrict__ x, const float* __restrict__ gamma, const float* __restrict__ beta) {
  __shared__ float red[8];
  const int tid = threadIdx.x;
  const long row = blockIdx.x;
  float4 v = *(const float4*)(x + row * EMBED + tid * 4);
  float s = v.x + v.y + v.z + v.w;
  float sq = v.x * v.x + v.y * v.y + v.z * v.z + v.w * v.w;
#pragma unroll
  for (int off = 1; off < 64; off <<= 1) {
    s += __shfl_xor(s, off);
    sq += __shfl_xor(sq, off);
  }
  if ((tid & 63) == 0) {
    red[(tid >> 6) * 2] = s;
    red[(tid >> 6) * 2 + 1] = sq;
  }
  __syncthreads();
  s = red[0] + red[2] + red[4] + red[6];
  sq = red[1] + red[3] + red[5] + red[7];
  float mu = s * (1.f / EMBED);
  float var = sq * (1.f / EMBED) - mu * mu;
  float rstd = rsqrtf(var + 1e-5f);
  float4 g = *(const float4*)(gamma + tid * 4);
  float4 bt = *(const float4*)(beta + tid * 4);
  float4 ov;
  ov.x = (v.x - mu) * rstd * g.x + bt.x;
  ov.y = (v.y - mu) * rstd * g.y + bt.y;
  ov.z = (v.z - mu) * rstd * g.z + bt.z;
  ov.w = (v.w - mu) * rstd * g.w + bt.w;
  *(float4*)(x + row * EMBED + tid * 4) = ov;
}

extern "C" void kernel_launch(void* const* d_in, const int* in_sizes, int n_in,
                              void* d_out, int out_size, void* d_ws, size_t ws_size,
                              hipStream_t stream) {
  const float* q     = (const float*)d_in[0];
  const float* kv    = (const float*)d_in[1];
  // d_in[2] = prompt_size (0, unused)
  const float* Wq    = (const float*)d_in[3];
  const float* bq    = (const float*)d_in[4];
  const float* Wk    = (const float*)d_in[5];
  const float* bk    = (const float*)d_in[6];
  const float* Wv    = (const float*)d_in[7];
  const float* bv    = (const float*)d_in[8];
  const float* Wo    = (const float*)d_in[9];
  const float* bo    = (const float*)d_in[10];
  const float* gamma = (const float*)d_in[11];
  const float* beta  = (const float*)d_in[12];

  char* ws = (char*)d_ws;
  u16* qb  = (u16*)(ws + (0l  << 20));  // 8 MB
  u16* kvb = (u16*)(ws + (8l  << 20));  // 8 MB
  u16* wqb = (u16*)(ws + (16l << 20));  // 2 MB
  u16* wkb = (u16*)(ws + (18l << 20));
  u16* wvb = (u16*)(ws + (20l << 20));
  u16* wob = (u16*)(ws + (22l << 20));
  u16* Qh  = (u16*)(ws + (24l << 20));  // 8 MB [bh][L][64] (pre-scaled by QSCALE)
  u16* Kh  = (u16*)(ws + (32l << 20));  // 8 MB [bh][L][64]
  u16* Vt  = (u16*)(ws + (40l << 20));  // 8 MB [bh][64][L]
  u16* ctx = (u16*)(ws + (48l << 20));  // 8 MB [B][L][E]   (total 56 MB)
  float* out = (float*)d_out;

  cast_kernel<<<6144, 256, 0, stream>>>(q, kv, Wq, Wk, Wv, Wo, qb, kvb, wqb, wkb, wvb, wob);
  qkv_kernel<<<dim3(64, 8, 3), 256, 0, stream>>>(qb, kvb, wqb, wkb, wvb, bq, bk, bv, Qh, Kh, Vt);
  attn_kernel<<<512, 512, 0, stream>>>(Qh, Kh, Vt, ctx);
  oproj_kernel<<<dim3(64, 8), 256, 0, stream>>>(ctx, wob, bo, q, out);
  ln_kernel<<<4096, 256, 0, stream>>>(out, gamma, beta);
}

// Round 10
// 207.531 us; speedup vs baseline: 1.0805x; 1.0805x over previous
//
#include <hip/hip_runtime.h>

typedef unsigned short u16;
typedef unsigned int u32;
typedef __attribute__((ext_vector_type(8))) __bf16 bf16x8;
typedef __attribute__((ext_vector_type(4))) float f32x4;
typedef __attribute__((ext_vector_type(16))) float f32x16;

#define EMBED 1024
#define NB 2
#define LQ 2048
#define HEADS 16
#define DH 64
// log2(e) / sqrt(64) -- folded into Q at projection time
#define QSCALE 0.18033688011112042f

__device__ __forceinline__ u16 f2bf(float f) {
  u32 u = __float_as_uint(f);
  u32 r = (u + 0x7FFFu + ((u >> 16) & 1u)) >> 16;  // RNE
  return (u16)r;
}

__device__ __forceinline__ void glds16(const void* g, void* l) {
  __builtin_amdgcn_global_load_lds((const __attribute__((address_space(1))) void*)g,
                                   (__attribute__((address_space(3))) void*)l, 16, 0, 0);
}

__device__ __forceinline__ f32x4 mfma16(bf16x8 a, bf16x8 b, f32x4 c) {
  return __builtin_amdgcn_mfma_f32_16x16x32_bf16(a, b, c, 0, 0, 0);
}
__device__ __forceinline__ f32x16 mfma32(bf16x8 a, bf16x8 b, f32x16 c) {
  return __builtin_amdgcn_mfma_f32_32x32x16_bf16(a, b, c, 0, 0, 0);
}

// v_permlane32_swap_b32: a[l>=32] <-> b[l-32]. Register-only exchange.
__device__ __forceinline__ void pl32(u32& a, u32& b) {
  asm("v_permlane32_swap_b32 %0, %1" : "+v"(a), "+v"(b));
}

// pack two floats to bf16 pair (truncating): low = a, high = b
__device__ __forceinline__ u32 packbf(float a, float b) {
  return __builtin_amdgcn_perm(__float_as_uint(b), __float_as_uint(a), 0x07060302u);
}

// ---------------- cast fp32 -> bf16 for activations + weights ----------------
__global__ __launch_bounds__(256) void cast_kernel(
    const float* __restrict__ q, const float* __restrict__ kv,
    const float* __restrict__ wq, const float* __restrict__ wk,
    const float* __restrict__ wv, const float* __restrict__ wo,
    u16* __restrict__ qb, u16* __restrict__ kvb, u16* __restrict__ wqb,
    u16* __restrict__ wkb, u16* __restrict__ wvb, u16* __restrict__ wob) {
  int bid = blockIdx.x;
  const float* src;
  u16* dst;
  long base;
  if (bid < 2048) {
    src = q; dst = qb; base = (long)bid * 2048;
  } else if (bid < 4096) {
    src = kv; dst = kvb; base = (long)(bid - 2048) * 2048;
  } else {
    int wsel = (bid - 4096) >> 9;
    int wb = (bid - 4096) & 511;
    if (wsel == 0) { src = wq; dst = wqb; }
    else if (wsel == 1) { src = wk; dst = wkb; }
    else if (wsel == 2) { src = wv; dst = wvb; }
    else { src = wo; dst = wob; }
    base = (long)wb * 2048;
  }
  long e = base + (long)threadIdx.x * 8;
  float4 f0 = *(const float4*)(src + e);
  float4 f1 = *(const float4*)(src + e + 4);
  uint4 o;
  o.x = (u32)f2bf(f0.x) | ((u32)f2bf(f0.y) << 16);
  o.y = (u32)f2bf(f0.z) | ((u32)f2bf(f0.w) << 16);
  o.z = (u32)f2bf(f1.x) | ((u32)f2bf(f1.y) << 16);
  o.w = (u32)f2bf(f1.z) | ((u32)f2bf(f1.w) << 16);
  *(uint4*)(dst + e) = o;
}

// ------------- GEMM: C = A @ W^T (+bias, mode-specific epilogue), BK=64 ------
// R7-verified structure (best total 206.2us): 2 __syncthreads per K-step,
// per-ki fragment loads, compiler-scheduled. R9's BK=32 counted-ring REGRESSED
// (qkv 44->55us: compute/barrier halved, asm clobbers pinned the schedule) --
// for this small-K shape the compiler-scheduled 2-barrier loop is the local
// optimum. mode 0: Q -> [bh][L][64] scaled; 1: K same; 2: V^T (b64 stores);
// 3: fp32 out = acc + bias + resid.
template <int IT>
__device__ __forceinline__ void gemm_core(
    u16* As, u16* Bs, const u16* __restrict__ A, const u16* __restrict__ W,
    const float* __restrict__ bias, const float* __restrict__ resid,
    void* __restrict__ outp, int mode, int bx, int by) {
  const int K = EMBED;
  const int TM = IT * 32;
  const int tid = threadIdx.x;
  const int lane = tid & 63;
  const int wv = tid >> 6;
  const int wm = wv >> 1, wn = wv & 1;
  const int l16 = lane & 15, quad = lane >> 4;
  const long tile_m = (long)bx * TM;
  const long tile_n = (long)by * 128;

  f32x4 z4 = {0.f, 0.f, 0.f, 0.f};
  f32x4 acc[IT][4];
#pragma unroll
  for (int i = 0; i < IT; i++)
#pragma unroll
    for (int j = 0; j < 4; j++) acc[i][j] = z4;

  for (int k0 = 0; k0 < K; k0 += 64) {
    // stage A: TM rows x 8 chunks(16B), XOR swizzle cc ^ (row&7)
#pragma unroll
    for (int it = 0; it < TM / 32; it++) {
      int lin = it * 256 + tid;
      int row = lin >> 3, cc = lin & 7;
      glds16(A + (tile_m + row) * K + k0 + ((cc ^ (row & 7)) << 3), As + lin * 8);
    }
#pragma unroll
    for (int it = 0; it < 4; it++) {
      int lin = it * 256 + tid;
      int row = lin >> 3, cc = lin & 7;
      glds16(W + (tile_n + row) * K + k0 + ((cc ^ (row & 7)) << 3), Bs + lin * 8);
    }
    __syncthreads();
#pragma unroll
    for (int ki = 0; ki < 2; ki++) {
      bf16x8 af[IT], bfr[4];
#pragma unroll
      for (int i = 0; i < IT; i++) {
        int row = wm * (IT * 16) + i * 16 + l16;
        af[i] = *(const bf16x8*)(As + row * 64 + (((ki * 4 + quad) ^ (row & 7)) << 3));
      }
#pragma unroll
      for (int j = 0; j < 4; j++) {
        int row = wn * 64 + j * 16 + l16;
        bfr[j] = *(const bf16x8*)(Bs + row * 64 + (((ki * 4 + quad) ^ (row & 7)) << 3));
      }
#pragma unroll
      for (int i = 0; i < IT; i++)
#pragma unroll
        for (int j = 0; j < 4; j++) acc[i][j] = mfma16(af[i], bfr[j], acc[i][j]);
    }
    __syncthreads();
  }

  // epilogue: C/D layout col=lane&15, row=quad*4+r (R7 coalesced scalar forms)
#pragma unroll
  for (int j = 0; j < 4; j++) {
    int gn = (int)tile_n + wn * 64 + j * 16 + l16;
    float bv = bias[gn];
#pragma unroll
    for (int i = 0; i < IT; i++) {
      long gm0 = tile_m + wm * (IT * 16) + i * 16 + quad * 4;
      if (mode == 3) {
#pragma unroll
        for (int r = 0; r < 4; r++) {
          long idx = (gm0 + r) * EMBED + gn;
          ((float*)outp)[idx] = acc[i][j][r] + bv + resid[idx];
        }
      } else if (mode == 2) {
        // V^T: lane's 4 values are consecutive l at fixed dh -> one b64 store
        int b = (int)(gm0 >> 11), l = (int)(gm0 & 2047);
        int hh = gn >> 6, dh = gn & 63;
        uint2 pk;
        pk.x = (u32)f2bf(acc[i][j][0] + bv) | ((u32)f2bf(acc[i][j][1] + bv) << 16);
        pk.y = (u32)f2bf(acc[i][j][2] + bv) | ((u32)f2bf(acc[i][j][3] + bv) << 16);
        *(uint2*)((u16*)outp + (long)((b * HEADS + hh) * DH + dh) * LQ + l) = pk;
      } else {
#pragma unroll
        for (int r = 0; r < 4; r++) {
          long gm = gm0 + r;
          float v = acc[i][j][r] + bv;
          if (mode == 0) v *= QSCALE;
          int b = (int)(gm >> 11), l = (int)(gm & 2047);
          int hh = gn >> 6, dh = gn & 63;
          ((u16*)outp)[(long)((b * HEADS + hh) * LQ + l) * DH + dh] = f2bf(v);
        }
      }
    }
  }
}

// XCD-swizzled block mapping (the one technique verified on-chip this session:
// attn FETCH 70->12 MB). Default dispatch scatters each weight-panel's blocks
// across all XCDs -> every XCD touches the full 8 MB A matrix (> 4 MB L2).
// Bijective remap (512 = 8 x 64): XCD x owns bx in [8x,8x+8) for all by ->
// per-XCD set = A 1 MB + W 2 MB < L2. (3D grid: flat%8 = blockIdx.x%8 since
// 512%8==0.)
__device__ __forceinline__ void xcd_map(int id, int& bx, int& by) {
  int xcd = id & 7, j = id >> 3;
  bx = (xcd << 3) | (j & 7);
  by = j >> 3;
}

// IT=2 (64-row tiles): 1536 blocks, 24KB LDS -> 4+ blocks/CU for TLP.
__global__ __launch_bounds__(256, 4) void qkv_kernel(
    const u16* __restrict__ qb, const u16* __restrict__ kvb,
    const u16* __restrict__ wqb, const u16* __restrict__ wkb, const u16* __restrict__ wvb,
    const float* __restrict__ bq, const float* __restrict__ bk, const float* __restrict__ bv,
    u16* __restrict__ Qh, u16* __restrict__ Kh, u16* __restrict__ Vt) {
  __shared__ u16 As[64 * 64];    // 8 KB
  __shared__ u16 Bs[128 * 64];   // 16 KB
  int bx, by;
  xcd_map((int)blockIdx.x, bx, by);
  int z = blockIdx.y;
  if (z == 0)      gemm_core<2>(As, Bs, qb,  wqb, bq, nullptr, Qh, 0, bx, by);
  else if (z == 1) gemm_core<2>(As, Bs, kvb, wkb, bk, nullptr, Kh, 1, bx, by);
  else             gemm_core<2>(As, Bs, kvb, wvb, bv, nullptr, Vt, 2, bx, by);
}

__global__ __launch_bounds__(256, 4) void oproj_kernel(
    const u16* __restrict__ ctx, const u16* __restrict__ wob,
    const float* __restrict__ bo, const float* __restrict__ resid, float* __restrict__ out) {
  __shared__ u16 As[64 * 64];    // 8 KB
  __shared__ u16 Bs[128 * 64];   // 16 KB
  int bx, by;
  xcd_map((int)blockIdx.x, bx, by);
  gemm_core<2>(As, Bs, ctx, wob, bo, resid, out, 3, bx, by);
}

// ---- flash attention: 8-wave blocks (4 qsub x 2 key-halves), ring-4+vmcnt ---
// Verified at 44.3us (R8/R9): 512 threads = 8 waves = 4 qsub x 2 key-halves;
// wave (qsub,kh) owns 32 qrows x keys [32kh,32kh+32) of each 64-key tile;
// 2 blocks/CU = 4 waves/SIMD. ring-4 (slot t&3), stage t+2, counted
// s_waitcnt vmcnt(2), XCD swizzle (FETCH 70->12 MB verified). K-half partials
// merge additively via one LDS exchange reusing the ring after the loop.
__global__ __launch_bounds__(512, 4) void attn_kernel(
    const u16* __restrict__ Qh, const u16* __restrict__ Kh,
    const u16* __restrict__ Vt, u16* __restrict__ ctx) {
  __shared__ u16 KVs[4][2][64 * 64];  // 64 KB: ring[4] x [K/V] x 64x64
  const int tid = threadIdx.x;
  const int lane = tid & 63;
  const int wv = tid >> 6;            // 8 waves
  const int qsub = wv >> 1;           // 4 q-subtiles of 32 rows
  const int kh = wv & 1;              // key half within each 64-key tile
  const int l32 = lane & 31, h = lane >> 5;
  // XCD swizzle (XCD = blockIdx%8): XCD x -> swz in [64x, 64x+64) -> bh chunk
  const int bid = (int)blockIdx.x;
  const int swz = (bid & 7) * 64 + (bid >> 3);
  const int bh = swz >> 4, qt = swz & 15;
  const long qoff = (long)bh * (LQ * DH) + (long)qt * (128 * DH);
  const long koff = (long)bh * (LQ * DH);
  const long voff = (long)bh * (DH * LQ);
  const int qbase = qsub * 32;
  const int krow = kh * 32 + l32;     // wave's K-row (key) in the 64-key tile

// stage K/V tile t into ring slot N; 512 threads cover 8KB each in ONE pass
// -> 2 vm ops per wave per stage
#define STAGE_KV(t, N)                                                          \
  do {                                                                          \
    int row = tid >> 3, cc = tid & 7;                                           \
    glds16(Kh + koff + (long)((t) * 64 + row) * 64 + ((cc ^ (row & 7)) << 3),   \
           &KVs[N][0][0] + tid * 8);                                            \
    glds16(Vt + voff + (long)row * LQ + (t) * 64 + ((cc ^ (row & 7)) << 3),     \
           &KVs[N][1][0] + tid * 8);                                            \
  } while (0)

// counted-drain barrier: allow the W newest vmem ops to stay in flight.
#define SYNC(W)                                                                 \
  do {                                                                          \
    asm volatile("s_waitcnt vmcnt(" #W ")" ::: "memory");                       \
    __builtin_amdgcn_s_barrier();                                               \
    asm volatile("" ::: "memory");                                              \
  } while (0)

  // Q B-frags direct from global: qrow = qbase+l32, d-chunk = ks*16+8h+(0..7)
  bf16x8 bq[4];
  {
    const u16* qp = Qh + qoff + (qbase + l32) * 64 + h * 8;
#pragma unroll
    for (int ks = 0; ks < 4; ks++) bq[ks] = *(const bf16x8*)(qp + ks * 16);
  }

  STAGE_KV(0, 0);
  STAGE_KV(1, 1);
  STAGE_KV(2, 2);
  SYNC(2);  // bq + tiles 0,1 landed; tile 2's 2 ops may fly

  f32x16 z16 = {0.f, 0.f, 0.f, 0.f, 0.f, 0.f, 0.f, 0.f,
                0.f, 0.f, 0.f, 0.f, 0.f, 0.f, 0.f, 0.f};
  f32x16 ot[2];
  ot[0] = z16;
  ot[1] = z16;
  f32x16 st;            // S^T scores for this wave's 32 keys x 32 qrows
  uint2 pk[4];          // packed exp'd scores (this wave's key half)
  float2 ls2 = {0.f, 0.f};

// S^T = K(half kh) . Q^T from ring slot C into st; inline ds_reads.
// ks==0 uses the hoisted zero vector as C -> no accumulator zero-init movs.
#define DO_S(C)                                                                  \
  do {                                                                           \
    __builtin_amdgcn_s_setprio(1);                                               \
    _Pragma("unroll") for (int ks = 0; ks < 4; ks++) {                           \
      bf16x8 ak = *(const bf16x8*)(&KVs[C][0][0] + krow * 64 +                   \
                                   (((ks * 2 + h) ^ (krow & 7)) << 3));          \
      st = mfma32(ak, bq[ks], (ks == 0) ? z16 : st);                             \
    }                                                                            \
    __builtin_amdgcn_s_setprio(0);                                               \
  } while (0)

// p = 2^st via raw v_exp_f32; lane's scores: qrow = qbase+l32,
// key = 32kh + 8g + 4h + r
#define DO_SM()                                                                  \
  do {                                                                           \
    _Pragma("unroll") for (int g = 0; g < 4; g++) {                              \
      float p0 = __builtin_amdgcn_exp2f(st[g * 4 + 0]);                          \
      float p1 = __builtin_amdgcn_exp2f(st[g * 4 + 1]);                          \
      float p2 = __builtin_amdgcn_exp2f(st[g * 4 + 2]);                          \
      float p3 = __builtin_amdgcn_exp2f(st[g * 4 + 3]);                          \
      ls2.x += p0 + p2;                                                          \
      ls2.y += p1 + p3;                                                          \
      pk[g].x = packbf(p0, p1);                                                  \
      pk[g].y = packbf(p2, p3);                                                  \
    }                                                                            \
  } while (0)

// O^T(partial over this wave's keys) += V^T . P from ring slot P.
// kstep s' in {0,1} covers keys 32kh+16s'..+15; B-frag words (keys
// 32kh+16s'+8h+{0..7}) from own pk + cross-half partner via permlane32_swap.
// V^T chunk c = (2*(2kh+s')+h) -> keys c*8..c*8+7.
#define DO_PV(P)                                                                 \
  do {                                                                           \
    _Pragma("unroll") for (int s = 0; s < 2; s++) {                              \
      uint2 wa = pk[s * 2];                                                      \
      uint2 wb = pk[s * 2 + 1];                                                  \
      u32 a0 = wa.x, b0 = wb.x, a1 = wa.y, b1 = wb.y;                            \
      pl32(a0, b0);                                                              \
      pl32(a1, b1);                                                              \
      union { u32 u[4]; bf16x8 v; } bp;                                          \
      bp.u[0] = a0;                                                              \
      bp.u[1] = a1;                                                              \
      bp.u[2] = b0;                                                              \
      bp.u[3] = b1;                                                              \
      __builtin_amdgcn_s_setprio(1);                                             \
      _Pragma("unroll") for (int mt2 = 0; mt2 < 2; mt2++) {                      \
        int row = mt2 * 32 + l32;                                                \
        int c = ((2 * kh + s) << 1) + h;                                         \
        bf16x8 av = *(const bf16x8*)(&KVs[P][1][0] + row * 64 +                  \
                                     ((c ^ (row & 7)) << 3));                    \
        ot[mt2] = mfma32(av, bp.v, ot[mt2]);                                     \
      }                                                                          \
      __builtin_amdgcn_s_setprio(0);                                             \
    }                                                                            \
  } while (0)

// iteration (tile kt): stage kt+2 -> N; softmax of kt-1 (st, WAR before S
// overwrites); S of kt from C; PV of kt-1 from P; counted barrier.
#define AITER(kt, P, C, N, W)                                                    \
  do {                                                                           \
    if ((kt) + 2 < 32) STAGE_KV((kt) + 2, N);                                    \
    DO_SM();                                                                     \
    DO_S(C);                                                                     \
    DO_PV(P);                                                                    \
    SYNC(W);                                                                     \
  } while (0)

  DO_S(0);  // prologue: scores of tile 0 (softmax'd in iter 1)

  AITER(1, 0, 1, 3, 2);
  for (int k0 = 2; k0 < 30; k0 += 4) {  // k0 = 2,6,...,26 -> kt = 2..29
    AITER(k0 + 0, 1, 2, 0, 2);
    AITER(k0 + 1, 2, 3, 1, 2);
    AITER(k0 + 2, 3, 0, 2, 2);
    AITER(k0 + 3, 0, 1, 3, 2);
  }
  AITER(30, 1, 2, 0, 0);  // no stage; full drain so tile 31 is landed
  AITER(31, 2, 3, 1, 0);  // no stage
  // tail: softmax + PV of tile 31 (slot 3)
  DO_SM();
  DO_PV(3);

#undef STAGE_KV
#undef SYNC
#undef DO_S
#undef DO_SM
#undef DO_PV
#undef AITER

  // partial lsum: fold float2 + combine the two lane-halves (same qrow)
  float lsum = ls2.x + ls2.y;
  lsum += __shfl_xor(lsum, 32);

  // ---- merge the two key-halves (additive; ring LDS reused) ----
  // mrg[qsub][lane][36pad]: 36 floats stride = 144B (16B-aligned, 4-way max)
  float* mrgf = (float*)(&KVs[0][0][0]);
  float* mlsf = mrgf + 4 * 64 * 36;  // 36864B + 1KB <= 64KB
  __syncthreads();  // all ring reads done before overwrite
  if (kh == 1) {
    int mbase = (qsub * 64 + lane) * 36;
#pragma unroll
    for (int mt2 = 0; mt2 < 2; mt2++)
#pragma unroll
      for (int e = 0; e < 16; e++) mrgf[mbase + mt2 * 16 + e] = ot[mt2][e];
    mlsf[qsub * 64 + lane] = lsum;
  }
  __syncthreads();
  if (kh == 0) {
    int mbase = (qsub * 64 + lane) * 36;
    lsum += mlsf[qsub * 64 + lane];
    float inv = 1.0f / lsum;
    // epilogue: lane holds qrow = qt*128 + qbase + l32, d = mt2*32 + g*8+4h+r
    const int b = bh >> 4, head = bh & 15;
    int qrow = qt * 128 + qbase + l32;
    long base = (long)(b * LQ + qrow) * EMBED + head * DH;
#pragma unroll
    for (int mt2 = 0; mt2 < 2; mt2++) {
#pragma unroll
      for (int g = 0; g < 4; g++) {
        float o0 = (ot[mt2][g * 4 + 0] + mrgf[mbase + mt2 * 16 + g * 4 + 0]) * inv;
        float o1 = (ot[mt2][g * 4 + 1] + mrgf[mbase + mt2 * 16 + g * 4 + 1]) * inv;
        float o2 = (ot[mt2][g * 4 + 2] + mrgf[mbase + mt2 * 16 + g * 4 + 2]) * inv;
        float o3 = (ot[mt2][g * 4 + 3] + mrgf[mbase + mt2 * 16 + g * 4 + 3]) * inv;
        uint2 pkk;
        pkk.x = (u32)f2bf(o0) | ((u32)f2bf(o1) << 16);
        pkk.y = (u32)f2bf(o2) | ((u32)f2bf(o3) << 16);
        *(uint2*)(ctx + base + mt2 * 32 + g * 8 + 4 * h) = pkk;
      }
    }
  }
}

// ---------------- LayerNorm in place: one WAVE per row ----------------
// 4 rows per 256-thr block; 16 elems/lane; wave-only shuffle reduce (no LDS,
// no barrier). Verified correct in R8 (confounded there with bad epilogues).
__global__ __launch_bounds__(256) void ln_kernel(
    float* __restrict__ x, const float* __restrict__ gamma, const float* __restrict__ beta) {
  const int lane = threadIdx.x & 63;
  const int wid = threadIdx.x >> 6;
  const long row = (long)blockIdx.x * 4 + wid;
  float* xr = x + row * EMBED;
  float4 v[4];
  float s = 0.f, sq = 0.f;
#pragma unroll
  for (int k = 0; k < 4; k++) {
    v[k] = *(const float4*)(xr + k * 256 + lane * 4);
    s += v[k].x + v[k].y + v[k].z + v[k].w;
    sq += v[k].x * v[k].x + v[k].y * v[k].y + v[k].z * v[k].z + v[k].w * v[k].w;
  }
#pragma unroll
  for (int off = 1; off < 64; off <<= 1) {
    s += __shfl_xor(s, off);
    sq += __shfl_xor(sq, off);
  }
  float mu = s * (1.f / EMBED);
  float var = sq * (1.f / EMBED) - mu * mu;
  float rstd = rsqrtf(var + 1e-5f);
#pragma unroll
  for (int k = 0; k < 4; k++) {
    float4 g = *(const float4*)(gamma + k * 256 + lane * 4);
    float4 bt = *(const float4*)(beta + k * 256 + lane * 4);
    float4 ov;
    ov.x = (v[k].x - mu) * rstd * g.x + bt.x;
    ov.y = (v[k].y - mu) * rstd * g.y + bt.y;
    ov.z = (v[k].z - mu) * rstd * g.z + bt.z;
    ov.w = (v[k].w - mu) * rstd * g.w + bt.w;
    *(float4*)(xr + k * 256 + lane * 4) = ov;
  }
}

extern "C" void kernel_launch(void* const* d_in, const int* in_sizes, int n_in,
                              void* d_out, int out_size, void* d_ws, size_t ws_size,
                              hipStream_t stream) {
  const float* q     = (const float*)d_in[0];
  const float* kv    = (const float*)d_in[1];
  // d_in[2] = prompt_size (0, unused)
  const float* Wq    = (const float*)d_in[3];
  const float* bq    = (const float*)d_in[4];
  const float* Wk    = (const float*)d_in[5];
  const float* bk    = (const float*)d_in[6];
  const float* Wv    = (const float*)d_in[7];
  const float* bv    = (const float*)d_in[8];
  const float* Wo    = (const float*)d_in[9];
  const float* bo    = (const float*)d_in[10];
  const float* gamma = (const float*)d_in[11];
  const float* beta  = (const float*)d_in[12];

  char* ws = (char*)d_ws;
  u16* qb  = (u16*)(ws + (0l  << 20));  // 8 MB
  u16* kvb = (u16*)(ws + (8l  << 20));  // 8 MB
  u16* wqb = (u16*)(ws + (16l << 20));  // 2 MB
  u16* wkb = (u16*)(ws + (18l << 20));
  u16* wvb = (u16*)(ws + (20l << 20));
  u16* wob = (u16*)(ws + (22l << 20));
  u16* Qh  = (u16*)(ws + (24l << 20));  // 8 MB [bh][L][64] (pre-scaled by QSCALE)
  u16* Kh  = (u16*)(ws + (32l << 20));  // 8 MB [bh][L][64]
  u16* Vt  = (u16*)(ws + (40l << 20));  // 8 MB [bh][64][L]
  u16* ctx = (u16*)(ws + (48l << 20));  // 8 MB [B][L][E]   (total 56 MB)
  float* out = (float*)d_out;

  cast_kernel<<<6144, 256, 0, stream>>>(q, kv, Wq, Wk, Wv, Wo, qb, kvb, wqb, wkb, wvb, wob);
  qkv_kernel<<<dim3(512, 3), 256, 0, stream>>>(qb, kvb, wqb, wkb, wvb, bq, bk, bv, Qh, Kh, Vt);
  attn_kernel<<<512, 512, 0, stream>>>(Qh, Kh, Vt, ctx);
  oproj_kernel<<<512, 256, 0, stream>>>(ctx, wob, bo, q, out);
  ln_kernel<<<1024, 256, 0, stream>>>(out, gamma, beta);
}

// Round 11
// 203.388 us; speedup vs baseline: 1.1026x; 1.0204x over previous
//
#include <hip/hip_runtime.h>

typedef unsigned short u16;
typedef unsigned int u32;
typedef __attribute__((ext_vector_type(8))) __bf16 bf16x8;
typedef __attribute__((ext_vector_type(4))) float f32x4;
typedef __attribute__((ext_vector_type(16))) float f32x16;

#define EMBED 1024
#define NB 2
#define LQ 2048
#define HEADS 16
#define DH 64
// log2(e) / sqrt(64) -- folded into Q at projection time
#define QSCALE 0.18033688011112042f

__device__ __forceinline__ u16 f2bf(float f) {
  u32 u = __float_as_uint(f);
  u32 r = (u + 0x7FFFu + ((u >> 16) & 1u)) >> 16;  // RNE
  return (u16)r;
}

__device__ __forceinline__ void glds16(const void* g, void* l) {
  __builtin_amdgcn_global_load_lds((const __attribute__((address_space(1))) void*)g,
                                   (__attribute__((address_space(3))) void*)l, 16, 0, 0);
}

__device__ __forceinline__ f32x4 mfma16(bf16x8 a, bf16x8 b, f32x4 c) {
  return __builtin_amdgcn_mfma_f32_16x16x32_bf16(a, b, c, 0, 0, 0);
}
__device__ __forceinline__ f32x16 mfma32(bf16x8 a, bf16x8 b, f32x16 c) {
  return __builtin_amdgcn_mfma_f32_32x32x16_bf16(a, b, c, 0, 0, 0);
}

// v_permlane32_swap_b32: a[l>=32] <-> b[l-32]. Register-only exchange.
__device__ __forceinline__ void pl32(u32& a, u32& b) {
  asm("v_permlane32_swap_b32 %0, %1" : "+v"(a), "+v"(b));
}

// pack two floats to bf16 pair (truncating): low = a, high = b
__device__ __forceinline__ u32 packbf(float a, float b) {
  return __builtin_amdgcn_perm(__float_as_uint(b), __float_as_uint(a), 0x07060302u);
}

// ---------------- cast fp32 -> bf16 for activations + weights ----------------
__global__ __launch_bounds__(256) void cast_kernel(
    const float* __restrict__ q, const float* __restrict__ kv,
    const float* __restrict__ wq, const float* __restrict__ wk,
    const float* __restrict__ wv, const float* __restrict__ wo,
    u16* __restrict__ qb, u16* __restrict__ kvb, u16* __restrict__ wqb,
    u16* __restrict__ wkb, u16* __restrict__ wvb, u16* __restrict__ wob) {
  int bid = blockIdx.x;
  const float* src;
  u16* dst;
  long base;
  if (bid < 2048) {
    src = q; dst = qb; base = (long)bid * 2048;
  } else if (bid < 4096) {
    src = kv; dst = kvb; base = (long)(bid - 2048) * 2048;
  } else {
    int wsel = (bid - 4096) >> 9;
    int wb = (bid - 4096) & 511;
    if (wsel == 0) { src = wq; dst = wqb; }
    else if (wsel == 1) { src = wk; dst = wkb; }
    else if (wsel == 2) { src = wv; dst = wvb; }
    else { src = wo; dst = wob; }
    base = (long)wb * 2048;
  }
  long e = base + (long)threadIdx.x * 8;
  float4 f0 = *(const float4*)(src + e);
  float4 f1 = *(const float4*)(src + e + 4);
  uint4 o;
  o.x = (u32)f2bf(f0.x) | ((u32)f2bf(f0.y) << 16);
  o.y = (u32)f2bf(f0.z) | ((u32)f2bf(f0.w) << 16);
  o.z = (u32)f2bf(f1.x) | ((u32)f2bf(f1.y) << 16);
  o.w = (u32)f2bf(f1.z) | ((u32)f2bf(f1.w) << 16);
  *(uint4*)(dst + e) = o;
}

// ------------- GEMM: C = A @ W^T (+bias, mode-specific epilogue), BK=64 ------
// R7-verified structure: 2 __syncthreads per K-step, per-ki fragment loads,
// compiler-scheduled (R9's counted-ring BK=32 regressed -- do not touch).
// mode 0: Q -> [bh][L][64] scaled; 1: K same; 2: V^T (b64 stores);
// 3: fp32 out = acc + bias + resid.
template <int IT>
__device__ __forceinline__ void gemm_core(
    u16* As, u16* Bs, const u16* __restrict__ A, const u16* __restrict__ W,
    const float* __restrict__ bias, const float* __restrict__ resid,
    void* __restrict__ outp, int mode, int bx, int by) {
  const int K = EMBED;
  const int TM = IT * 32;
  const int tid = threadIdx.x;
  const int lane = tid & 63;
  const int wv = tid >> 6;
  const int wm = wv >> 1, wn = wv & 1;
  const int l16 = lane & 15, quad = lane >> 4;
  const long tile_m = (long)bx * TM;
  const long tile_n = (long)by * 128;

  f32x4 z4 = {0.f, 0.f, 0.f, 0.f};
  f32x4 acc[IT][4];
#pragma unroll
  for (int i = 0; i < IT; i++)
#pragma unroll
    for (int j = 0; j < 4; j++) acc[i][j] = z4;

  for (int k0 = 0; k0 < K; k0 += 64) {
#pragma unroll
    for (int it = 0; it < TM / 32; it++) {
      int lin = it * 256 + tid;
      int row = lin >> 3, cc = lin & 7;
      glds16(A + (tile_m + row) * K + k0 + ((cc ^ (row & 7)) << 3), As + lin * 8);
    }
#pragma unroll
    for (int it = 0; it < 4; it++) {
      int lin = it * 256 + tid;
      int row = lin >> 3, cc = lin & 7;
      glds16(W + (tile_n + row) * K + k0 + ((cc ^ (row & 7)) << 3), Bs + lin * 8);
    }
    __syncthreads();
#pragma unroll
    for (int ki = 0; ki < 2; ki++) {
      bf16x8 af[IT], bfr[4];
#pragma unroll
      for (int i = 0; i < IT; i++) {
        int row = wm * (IT * 16) + i * 16 + l16;
        af[i] = *(const bf16x8*)(As + row * 64 + (((ki * 4 + quad) ^ (row & 7)) << 3));
      }
#pragma unroll
      for (int j = 0; j < 4; j++) {
        int row = wn * 64 + j * 16 + l16;
        bfr[j] = *(const bf16x8*)(Bs + row * 64 + (((ki * 4 + quad) ^ (row & 7)) << 3));
      }
#pragma unroll
      for (int i = 0; i < IT; i++)
#pragma unroll
        for (int j = 0; j < 4; j++) acc[i][j] = mfma16(af[i], bfr[j], acc[i][j]);
    }
    __syncthreads();
  }

  // epilogue: C/D layout col=lane&15, row=quad*4+r (coalesced scalar forms)
#pragma unroll
  for (int j = 0; j < 4; j++) {
    int gn = (int)tile_n + wn * 64 + j * 16 + l16;
    float bv = bias[gn];
#pragma unroll
    for (int i = 0; i < IT; i++) {
      long gm0 = tile_m + wm * (IT * 16) + i * 16 + quad * 4;
      if (mode == 3) {
#pragma unroll
        for (int r = 0; r < 4; r++) {
          long idx = (gm0 + r) * EMBED + gn;
          ((float*)outp)[idx] = acc[i][j][r] + bv + resid[idx];
        }
      } else if (mode == 2) {
        int b = (int)(gm0 >> 11), l = (int)(gm0 & 2047);
        int hh = gn >> 6, dh = gn & 63;
        uint2 pk;
        pk.x = (u32)f2bf(acc[i][j][0] + bv) | ((u32)f2bf(acc[i][j][1] + bv) << 16);
        pk.y = (u32)f2bf(acc[i][j][2] + bv) | ((u32)f2bf(acc[i][j][3] + bv) << 16);
        *(uint2*)((u16*)outp + (long)((b * HEADS + hh) * DH + dh) * LQ + l) = pk;
      } else {
#pragma unroll
        for (int r = 0; r < 4; r++) {
          long gm = gm0 + r;
          float v = acc[i][j][r] + bv;
          if (mode == 0) v *= QSCALE;
          int b = (int)(gm >> 11), l = (int)(gm & 2047);
          int hh = gn >> 6, dh = gn & 63;
          ((u16*)outp)[(long)((b * HEADS + hh) * LQ + l) * DH + dh] = f2bf(v);
        }
      }
    }
  }
}

// -------- merged K+V projection core: ONE kvb staging, TWO weight panels ----
// K and V both consume kvb; running them in one block stages the A-tile once,
// shares the af fragment reads, and halves the KV barrier-sequence count.
// 16 MFMA per K-step (vs 8) -> 2x compute per barrier for the latency-bound
// shape. bf frags scoped so K-panel and V-panel regs don't co-live (VGPR
// ~110 < 128 cap; WRITE_SIZE is the spill tripwire). FP accumulation order
// per GEMM is unchanged -> bitwise-identical output (absmax tripwire).
__device__ __forceinline__ void kv_core(
    u16* As, u16* Bk, u16* Bv,
    const u16* __restrict__ A, const u16* __restrict__ Wk, const u16* __restrict__ Wv,
    const float* __restrict__ bkb, const float* __restrict__ bvb,
    u16* __restrict__ Kh, u16* __restrict__ Vt, int bx, int by) {
  const int K = EMBED;
  const int tid = threadIdx.x;
  const int lane = tid & 63;
  const int wvv = tid >> 6;
  const int wm = wvv >> 1, wn = wvv & 1;
  const int l16 = lane & 15, quad = lane >> 4;
  const long tile_m = (long)bx * 64;
  const long tile_n = (long)by * 128;

  f32x4 z4 = {0.f, 0.f, 0.f, 0.f};
  f32x4 accK[2][4], accV[2][4];
#pragma unroll
  for (int i = 0; i < 2; i++)
#pragma unroll
    for (int j = 0; j < 4; j++) { accK[i][j] = z4; accV[i][j] = z4; }

  for (int k0 = 0; k0 < K; k0 += 64) {
#pragma unroll
    for (int it = 0; it < 2; it++) {
      int lin = it * 256 + tid;
      int row = lin >> 3, cc = lin & 7;
      glds16(A + (tile_m + row) * K + k0 + ((cc ^ (row & 7)) << 3), As + lin * 8);
    }
#pragma unroll
    for (int it = 0; it < 4; it++) {
      int lin = it * 256 + tid;
      int row = lin >> 3, cc = lin & 7;
      glds16(Wk + (tile_n + row) * K + k0 + ((cc ^ (row & 7)) << 3), Bk + lin * 8);
      glds16(Wv + (tile_n + row) * K + k0 + ((cc ^ (row & 7)) << 3), Bv + lin * 8);
    }
    __syncthreads();
#pragma unroll
    for (int ki = 0; ki < 2; ki++) {
      bf16x8 af[2];
#pragma unroll
      for (int i = 0; i < 2; i++) {
        int row = wm * 32 + i * 16 + l16;
        af[i] = *(const bf16x8*)(As + row * 64 + (((ki * 4 + quad) ^ (row & 7)) << 3));
      }
      {
        bf16x8 bf[4];
#pragma unroll
        for (int j = 0; j < 4; j++) {
          int row = wn * 64 + j * 16 + l16;
          bf[j] = *(const bf16x8*)(Bk + row * 64 + (((ki * 4 + quad) ^ (row & 7)) << 3));
        }
#pragma unroll
        for (int i = 0; i < 2; i++)
#pragma unroll
          for (int j = 0; j < 4; j++) accK[i][j] = mfma16(af[i], bf[j], accK[i][j]);
      }
      {
        bf16x8 bf[4];
#pragma unroll
        for (int j = 0; j < 4; j++) {
          int row = wn * 64 + j * 16 + l16;
          bf[j] = *(const bf16x8*)(Bv + row * 64 + (((ki * 4 + quad) ^ (row & 7)) << 3));
        }
#pragma unroll
        for (int i = 0; i < 2; i++)
#pragma unroll
          for (int j = 0; j < 4; j++) accV[i][j] = mfma16(af[i], bf[j], accV[i][j]);
      }
    }
    __syncthreads();
  }

  // epilogues: K = mode-1 scalar coalesced; V = mode-2 b64 transpose store
#pragma unroll
  for (int j = 0; j < 4; j++) {
    int gn = (int)tile_n + wn * 64 + j * 16 + l16;
    float bK = bkb[gn];
    float bV = bvb[gn];
    int hh = gn >> 6, dh = gn & 63;
#pragma unroll
    for (int i = 0; i < 2; i++) {
      long gm0 = tile_m + wm * 32 + i * 16 + quad * 4;
      int b = (int)(gm0 >> 11), l0 = (int)(gm0 & 2047);
#pragma unroll
      for (int r = 0; r < 4; r++) {
        Kh[(long)((b * HEADS + hh) * LQ + (l0 + r)) * DH + dh] = f2bf(accK[i][j][r] + bK);
      }
      uint2 pk;
      pk.x = (u32)f2bf(accV[i][j][0] + bV) | ((u32)f2bf(accV[i][j][1] + bV) << 16);
      pk.y = (u32)f2bf(accV[i][j][2] + bV) | ((u32)f2bf(accV[i][j][3] + bV) << 16);
      *(uint2*)(Vt + (long)((b * HEADS + hh) * DH + dh) * LQ + l0) = pk;
    }
  }
}

// XCD-swizzled block mapping (bijective for 512 = 8 x 64).
__device__ __forceinline__ void xcd_map(int id, int& bx, int& by) {
  int xcd = id & 7, j = id >> 3;
  bx = (xcd << 3) | (j & 7);
  by = j >> 3;
}

// z=0: Q projection (gemm_core mode 0). z=1: merged K+V (kv_core).
// dim3(512,2): flat dispatch fills all z=0 blocks into 2 slots/CU, then all
// z=1 into the other 2 -> each CU runs 2 Q + 2 KV blocks concurrently.
// LDS 8 + 2x16 = 40 KB -> 4 blocks/CU.
__global__ __launch_bounds__(256, 4) void qkv_kernel(
    const u16* __restrict__ qb, const u16* __restrict__ kvb,
    const u16* __restrict__ wqb, const u16* __restrict__ wkb, const u16* __restrict__ wvb,
    const float* __restrict__ bq, const float* __restrict__ bk, const float* __restrict__ bv,
    u16* __restrict__ Qh, u16* __restrict__ Kh, u16* __restrict__ Vt) {
  __shared__ u16 As[64 * 64];       // 8 KB
  __shared__ u16 Bs[2][128 * 64];   // 32 KB
  int bx, by;
  xcd_map((int)blockIdx.x, bx, by);
  if (blockIdx.y == 0)
    gemm_core<2>(As, Bs[0], qb, wqb, bq, nullptr, Qh, 0, bx, by);
  else
    kv_core(As, Bs[0], Bs[1], kvb, wkb, wvb, bk, bv, Kh, Vt, bx, by);
}

__global__ __launch_bounds__(256, 4) void oproj_kernel(
    const u16* __restrict__ ctx, const u16* __restrict__ wob,
    const float* __restrict__ bo, const float* __restrict__ resid, float* __restrict__ out) {
  __shared__ u16 As[64 * 64];    // 8 KB
  __shared__ u16 Bs[128 * 64];   // 16 KB
  int bx, by;
  xcd_map((int)blockIdx.x, bx, by);
  gemm_core<2>(As, Bs, ctx, wob, bo, resid, out, 3, bx, by);
}

// ---- flash attention: 8-wave blocks (4 qsub x 2 key-halves), ring-4+vmcnt ---
// Verified at 44.8us: 512 threads = 8 waves = 4 qsub x 2 key-halves; wave
// (qsub,kh) owns 32 qrows x keys [32kh,32kh+32) of each 64-key tile; 2
// blocks/CU = 4 waves/SIMD. ring-4 (slot t&3), stage t+2, counted vmcnt(2),
// XCD swizzle (FETCH 70->12 MB verified). K-half partials merge additively
// via one LDS exchange reusing the ring after the loop.
__global__ __launch_bounds__(512, 4) void attn_kernel(
    const u16* __restrict__ Qh, const u16* __restrict__ Kh,
    const u16* __restrict__ Vt, u16* __restrict__ ctx) {
  __shared__ u16 KVs[4][2][64 * 64];  // 64 KB: ring[4] x [K/V] x 64x64
  const int tid = threadIdx.x;
  const int lane = tid & 63;
  const int wv = tid >> 6;            // 8 waves
  const int qsub = wv >> 1;           // 4 q-subtiles of 32 rows
  const int kh = wv & 1;              // key half within each 64-key tile
  const int l32 = lane & 31, h = lane >> 5;
  const int bid = (int)blockIdx.x;
  const int swz = (bid & 7) * 64 + (bid >> 3);
  const int bh = swz >> 4, qt = swz & 15;
  const long qoff = (long)bh * (LQ * DH) + (long)qt * (128 * DH);
  const long koff = (long)bh * (LQ * DH);
  const long voff = (long)bh * (DH * LQ);
  const int qbase = qsub * 32;
  const int krow = kh * 32 + l32;     // wave's K-row (key) in the 64-key tile

#define STAGE_KV(t, N)                                                          \
  do {                                                                          \
    int row = tid >> 3, cc = tid & 7;                                           \
    glds16(Kh + koff + (long)((t) * 64 + row) * 64 + ((cc ^ (row & 7)) << 3),   \
           &KVs[N][0][0] + tid * 8);                                            \
    glds16(Vt + voff + (long)row * LQ + (t) * 64 + ((cc ^ (row & 7)) << 3),     \
           &KVs[N][1][0] + tid * 8);                                            \
  } while (0)

#define SYNC(W)                                                                 \
  do {                                                                          \
    asm volatile("s_waitcnt vmcnt(" #W ")" ::: "memory");                       \
    __builtin_amdgcn_s_barrier();                                               \
    asm volatile("" ::: "memory");                                              \
  } while (0)

  // Q B-frags direct from global: qrow = qbase+l32, d-chunk = ks*16+8h+(0..7)
  bf16x8 bq[4];
  {
    const u16* qp = Qh + qoff + (qbase + l32) * 64 + h * 8;
#pragma unroll
    for (int ks = 0; ks < 4; ks++) bq[ks] = *(const bf16x8*)(qp + ks * 16);
  }

  STAGE_KV(0, 0);
  STAGE_KV(1, 1);
  STAGE_KV(2, 2);
  SYNC(2);  // bq + tiles 0,1 landed; tile 2's 2 ops may fly

  f32x16 z16 = {0.f, 0.f, 0.f, 0.f, 0.f, 0.f, 0.f, 0.f,
                0.f, 0.f, 0.f, 0.f, 0.f, 0.f, 0.f, 0.f};
  f32x16 ot[2];
  ot[0] = z16;
  ot[1] = z16;
  f32x16 st;            // S^T scores for this wave's 32 keys x 32 qrows
  uint2 pk[4];          // packed exp'd scores (this wave's key half)
  float2 ls2 = {0.f, 0.f};

#define DO_S(C)                                                                  \
  do {                                                                           \
    __builtin_amdgcn_s_setprio(1);                                               \
    _Pragma("unroll") for (int ks = 0; ks < 4; ks++) {                           \
      bf16x8 ak = *(const bf16x8*)(&KVs[C][0][0] + krow * 64 +                   \
                                   (((ks * 2 + h) ^ (krow & 7)) << 3));          \
      st = mfma32(ak, bq[ks], (ks == 0) ? z16 : st);                             \
    }                                                                            \
    __builtin_amdgcn_s_setprio(0);                                               \
  } while (0)

#define DO_SM()                                                                  \
  do {                                                                           \
    _Pragma("unroll") for (int g = 0; g < 4; g++) {                              \
      float p0 = __builtin_amdgcn_exp2f(st[g * 4 + 0]);                          \
      float p1 = __builtin_amdgcn_exp2f(st[g * 4 + 1]);                          \
      float p2 = __builtin_amdgcn_exp2f(st[g * 4 + 2]);                          \
      float p3 = __builtin_amdgcn_exp2f(st[g * 4 + 3]);                          \
      ls2.x += p0 + p2;                                                          \
      ls2.y += p1 + p3;                                                          \
      pk[g].x = packbf(p0, p1);                                                  \
      pk[g].y = packbf(p2, p3);                                                  \
    }                                                                            \
  } while (0)

#define DO_PV(P)                                                                 \
  do {                                                                           \
    _Pragma("unroll") for (int s = 0; s < 2; s++) {                              \
      uint2 wa = pk[s * 2];                                                      \
      uint2 wb = pk[s * 2 + 1];                                                  \
      u32 a0 = wa.x, b0 = wb.x, a1 = wa.y, b1 = wb.y;                            \
      pl32(a0, b0);                                                              \
      pl32(a1, b1);                                                              \
      union { u32 u[4]; bf16x8 v; } bp;                                          \
      bp.u[0] = a0;                                                              \
      bp.u[1] = a1;                                                              \
      bp.u[2] = b0;                                                              \
      bp.u[3] = b1;                                                              \
      __builtin_amdgcn_s_setprio(1);                                             \
      _Pragma("unroll") for (int mt2 = 0; mt2 < 2; mt2++) {                      \
        int row = mt2 * 32 + l32;                                                \
        int c = ((2 * kh + s) << 1) + h;                                         \
        bf16x8 av = *(const bf16x8*)(&KVs[P][1][0] + row * 64 +                  \
                                     ((c ^ (row & 7)) << 3));                    \
        ot[mt2] = mfma32(av, bp.v, ot[mt2]);                                     \
      }                                                                          \
      __builtin_amdgcn_s_setprio(0);                                             \
    }                                                                            \
  } while (0)

#define AITER(kt, P, C, N, W)                                                    \
  do {                                                                           \
    if ((kt) + 2 < 32) STAGE_KV((kt) + 2, N);                                    \
    DO_SM();                                                                     \
    DO_S(C);                                                                     \
    DO_PV(P);                                                                    \
    SYNC(W);                                                                     \
  } while (0)

  DO_S(0);  // prologue: scores of tile 0 (softmax'd in iter 1)

  AITER(1, 0, 1, 3, 2);
  for (int k0 = 2; k0 < 30; k0 += 4) {  // k0 = 2,6,...,26 -> kt = 2..29
    AITER(k0 + 0, 1, 2, 0, 2);
    AITER(k0 + 1, 2, 3, 1, 2);
    AITER(k0 + 2, 3, 0, 2, 2);
    AITER(k0 + 3, 0, 1, 3, 2);
  }
  AITER(30, 1, 2, 0, 0);  // no stage; full drain so tile 31 is landed
  AITER(31, 2, 3, 1, 0);  // no stage
  DO_SM();
  DO_PV(3);

#undef STAGE_KV
#undef SYNC
#undef DO_S
#undef DO_SM
#undef DO_PV
#undef AITER

  // partial lsum: fold float2 + combine the two lane-halves (same qrow)
  float lsum = ls2.x + ls2.y;
  lsum += __shfl_xor(lsum, 32);

  // ---- merge the two key-halves (additive; ring LDS reused) ----
  float* mrgf = (float*)(&KVs[0][0][0]);
  float* mlsf = mrgf + 4 * 64 * 36;  // 36864B + 1KB <= 64KB
  __syncthreads();  // all ring reads done before overwrite
  if (kh == 1) {
    int mbase = (qsub * 64 + lane) * 36;
#pragma unroll
    for (int mt2 = 0; mt2 < 2; mt2++)
#pragma unroll
      for (int e = 0; e < 16; e++) mrgf[mbase + mt2 * 16 + e] = ot[mt2][e];
    mlsf[qsub * 64 + lane] = lsum;
  }
  __syncthreads();
  if (kh == 0) {
    int mbase = (qsub * 64 + lane) * 36;
    lsum += mlsf[qsub * 64 + lane];
    float inv = 1.0f / lsum;
    const int b = bh >> 4, head = bh & 15;
    int qrow = qt * 128 + qbase + l32;
    long base = (long)(b * LQ + qrow) * EMBED + head * DH;
#pragma unroll
    for (int mt2 = 0; mt2 < 2; mt2++) {
#pragma unroll
      for (int g = 0; g < 4; g++) {
        float o0 = (ot[mt2][g * 4 + 0] + mrgf[mbase + mt2 * 16 + g * 4 + 0]) * inv;
        float o1 = (ot[mt2][g * 4 + 1] + mrgf[mbase + mt2 * 16 + g * 4 + 1]) * inv;
        float o2 = (ot[mt2][g * 4 + 2] + mrgf[mbase + mt2 * 16 + g * 4 + 2]) * inv;
        float o3 = (ot[mt2][g * 4 + 3] + mrgf[mbase + mt2 * 16 + g * 4 + 3]) * inv;
        uint2 pkk;
        pkk.x = (u32)f2bf(o0) | ((u32)f2bf(o1) << 16);
        pkk.y = (u32)f2bf(o2) | ((u32)f2bf(o3) << 16);
        *(uint2*)(ctx + base + mt2 * 32 + g * 8 + 4 * h) = pkk;
      }
    }
  }
}

// ---------------- LayerNorm in place: one WAVE per row ----------------
__global__ __launch_bounds__(256) void ln_kernel(
    float* __restrict__ x, const float* __restrict__ gamma, const float* __restrict__ beta) {
  const int lane = threadIdx.x & 63;
  const int wid = threadIdx.x >> 6;
  const long row = (long)blockIdx.x * 4 + wid;
  float* xr = x + row * EMBED;
  float4 v[4];
  float s = 0.f, sq = 0.f;
#pragma unroll
  for (int k = 0; k < 4; k++) {
    v[k] = *(const float4*)(xr + k * 256 + lane * 4);
    s += v[k].x + v[k].y + v[k].z + v[k].w;
    sq += v[k].x * v[k].x + v[k].y * v[k].y + v[k].z * v[k].z + v[k].w * v[k].w;
  }
#pragma unroll
  for (int off = 1; off < 64; off <<= 1) {
    s += __shfl_xor(s, off);
    sq += __shfl_xor(sq, off);
  }
  float mu = s * (1.f / EMBED);
  float var = sq * (1.f / EMBED) - mu * mu;
  float rstd = rsqrtf(var + 1e-5f);
#pragma unroll
  for (int k = 0; k < 4; k++) {
    float4 g = *(const float4*)(gamma + k * 256 + lane * 4);
    float4 bt = *(const float4*)(beta + k * 256 + lane * 4);
    float4 ov;
    ov.x = (v[k].x - mu) * rstd * g.x + bt.x;
    ov.y = (v[k].y - mu) * rstd * g.y + bt.y;
    ov.z = (v[k].z - mu) * rstd * g.z + bt.z;
    ov.w = (v[k].w - mu) * rstd * g.w + bt.w;
    *(float4*)(xr + k * 256 + lane * 4) = ov;
  }
}

extern "C" void kernel_launch(void* const* d_in, const int* in_sizes, int n_in,
                              void* d_out, int out_size, void* d_ws, size_t ws_size,
                              hipStream_t stream) {
  const float* q     = (const float*)d_in[0];
  const float* kv    = (const float*)d_in[1];
  // d_in[2] = prompt_size (0, unused)
  const float* Wq    = (const float*)d_in[3];
  const float* bq    = (const float*)d_in[4];
  const float* Wk    = (const float*)d_in[5];
  const float* bk    = (const float*)d_in[6];
  const float* Wv    = (const float*)d_in[7];
  const float* bv    = (const float*)d_in[8];
  const float* Wo    = (const float*)d_in[9];
  const float* bo    = (const float*)d_in[10];
  const float* gamma = (const float*)d_in[11];
  const float* beta  = (const float*)d_in[12];

  char* ws = (char*)d_ws;
  u16* qb  = (u16*)(ws + (0l  << 20));  // 8 MB
  u16* kvb = (u16*)(ws + (8l  << 20));  // 8 MB
  u16* wqb = (u16*)(ws + (16l << 20));  // 2 MB
  u16* wkb = (u16*)(ws + (18l << 20));
  u16* wvb = (u16*)(ws + (20l << 20));
  u16* wob = (u16*)(ws + (22l << 20));
  u16* Qh  = (u16*)(ws + (24l << 20));  // 8 MB [bh][L][64] (pre-scaled by QSCALE)
  u16* Kh  = (u16*)(ws + (32l << 20));  // 8 MB [bh][L][64]
  u16* Vt  = (u16*)(ws + (40l << 20));  // 8 MB [bh][64][L]
  u16* ctx = (u16*)(ws + (48l << 20));  // 8 MB [B][L][E]   (total 56 MB)
  float* out = (float*)d_out;

  cast_kernel<<<6144, 256, 0, stream>>>(q, kv, Wq, Wk, Wv, Wo, qb, kvb, wqb, wkb, wvb, wob);
  qkv_kernel<<<dim3(512, 2), 256, 0, stream>>>(qb, kvb, wqb, wkb, wvb, bq, bk, bv, Qh, Kh, Vt);
  attn_kernel<<<512, 512, 0, stream>>>(Qh, Kh, Vt, ctx);
  oproj_kernel<<<512, 256, 0, stream>>>(ctx, wob, bo, q, out);
  ln_kernel<<<1024, 256, 0, stream>>>(out, gamma, beta);
}